// Round 3
// baseline (449.518 us; speedup 1.0000x reference)
//
#include <hip/hip_runtime.h>
#include <stdint.h>

typedef unsigned short u16;
typedef __attribute__((ext_vector_type(4))) float f32x4;
typedef __attribute__((ext_vector_type(8))) short bf16x8;

static constexpr int S   = 2048;
static constexpr int DM  = 4096;  // model dim
static constexpr int NH  = 32;    // query heads
static constexpr int NKV = 8;     // kv heads
static constexpr int HD  = 128;   // head dim
static constexpr int LDQ = 5120;  // QK buffer row stride (Q 4096 | K 1024)

template<int V> struct ic { static constexpr int v = V; };

__device__ __forceinline__ u16 f2bf(float f) {
    union { float f; unsigned u; } v; v.f = f;
    return (u16)((v.u + 0x7FFFu + ((v.u >> 16) & 1u)) >> 16);
}
__device__ __forceinline__ float bf2f(u16 h) {
    union { unsigned u; float f; } v; v.u = ((unsigned)h) << 16;
    return v.f;
}

__device__ __forceinline__ void mfma16(f32x4& d, bf16x8 a, bf16x8 b) {
    asm("v_mfma_f32_16x16x32_bf16 %0, %1, %2, %0" : "+v"(d) : "v"(a), "v"(b));
}

// async global->LDS, 16B/lane. LDS base is wave-uniform; HW adds lane*16.
__device__ __forceinline__ void gload_lds16(const u16* g, u16* lds) {
    __builtin_amdgcn_global_load_lds((__attribute__((address_space(1))) void*)g,
                                     (__attribute__((address_space(3))) void*)lds,
                                     16, 0, 0);
}

// ---------------- fp32 -> bf16 converts ----------------
__global__ __launch_bounds__(256) void cvt_kernel(const float* __restrict__ in,
                                                  u16* __restrict__ out, int n4) {
    int i = blockIdx.x * blockDim.x + threadIdx.x;
    int stride = gridDim.x * blockDim.x;
    for (; i < n4; i += stride) {
        float4 v = ((const float4*)in)[i];
        ushort4 o;
        o.x = f2bf(v.x); o.y = f2bf(v.y); o.z = f2bf(v.z); o.w = f2bf(v.w);
        ((ushort4*)out)[i] = o;
    }
}

// fused Wq|Wk|Wv -> contiguous bf16 [6144][4096]
__global__ __launch_bounds__(256) void cvt_qkv(const float* __restrict__ Wq,
                                               const float* __restrict__ Wk,
                                               const float* __restrict__ Wv,
                                               u16* __restrict__ out) {
    const int n4 = 6144 * 4096 / 4;
    int i = blockIdx.x * blockDim.x + threadIdx.x;
    int stride = gridDim.x * blockDim.x;
    for (; i < n4; i += stride) {
        float4 v;
        if (i < 4194304)       v = ((const float4*)Wq)[i];
        else if (i < 5242880)  v = ((const float4*)Wk)[i - 4194304];
        else                   v = ((const float4*)Wv)[i - 5242880];
        ushort4 o;
        o.x = f2bf(v.x); o.y = f2bf(v.y); o.z = f2bf(v.z); o.w = f2bf(v.w);
        ((ushort4*)out)[i] = o;
    }
}

// ---------------- RoPE cos/sin table ----------------
__global__ __launch_bounds__(256) void rope_table_kernel(float2* __restrict__ tbl) {
    int i = blockIdx.x * blockDim.x + threadIdx.x;
    if (i >= S * 64) return;
    int p = i >> 6, j = i & 63;
    float inv = powf(10000.0f, -(float)j / 64.0f);
    float a = (float)p * inv;
    tbl[i] = make_float2(cosf(a), sinf(a));
}

// ---------------- RoPE in-place on bf16, row stride ld, pair (d, d+64) ----------------
__global__ __launch_bounds__(256) void rope_kernel(u16* __restrict__ X,
                                                   const float2* __restrict__ tbl,
                                                   int nh, int ld, float scale) {
    int i = blockIdx.x * blockDim.x + threadIdx.x;
    int total = S * nh * 64;
    if (i >= total) return;
    int dd = i & 63;
    int t2 = i >> 6;
    int hh = t2 % nh;
    int s  = t2 / nh;
    size_t base = (size_t)s * ld + (size_t)hh * HD + dd;
    float x1 = bf2f(X[base]);
    float x2 = bf2f(X[base + 64]);
    float2 cs = tbl[(s << 6) + dd];
    X[base]      = f2bf((x1 * cs.x - x2 * cs.y) * scale);
    X[base + 64] = f2bf((x2 * cs.x + x1 * cs.y) * scale);
}

// ======================= 256x256 8-phase GEMM (8 waves, BK=64) =======================
// C = A(2048 x 4096) * Bt(N x 4096)^T.  K fixed = 4096 (64 K-tiles).
// MODE 0: QKV epilogue (n<5120 -> Cqk bf16 stride LDQ; else Vt[n-5120][m] bf16)
// MODE 1: Cf f32 row-major stride 4096.
// Schedule: per K-tile 4 phases; stage tile t+1 into idle buffer during window t;
// counted vmcnt: (6) at phase 2, (2) at phase 4 -- never 0 in the loop (T4).
// LDS reads XOR-swizzled (byte ^= (row&7)<<4); stage uses inverse-swizzled global src.
template<int MODE, int NBX>
__global__ __launch_bounds__(512, 2)
void gemm8(const u16* __restrict__ A, const u16* __restrict__ Bt,
           u16* __restrict__ Cqk, u16* __restrict__ Vt, float* __restrict__ Cf) {
    __shared__ u16 LA[2][256 * 64];
    __shared__ u16 LB[2][256 * 64];
    const int t = threadIdx.x;
    const int w = t >> 6, l = t & 63;
    const int r16 = l & 15, g4 = l >> 4;
    const int wm = w >> 2, wn = w & 3;

    // T1: XCD-aware swizzle. grid = 8 * NBX blocks, cpx = NBX -> one tile-row per XCD.
    const int id = blockIdx.x;
    const int sw = (id & 7) * NBX + (id >> 3);
    const int bx = sw % NBX, by = sw / NBX;
    const int m0 = by * 256, n0 = bx * 256;

    // stage B-tile (both halves, 4 gloads) for K-tile at col kt into buf b
    auto stB = [&](int kt, int b) {
#pragma unroll
        for (int i = 0; i < 4; ++i) {
            int c = i * 512 + t;
            int r = c >> 3, s = (c & 7) ^ (r & 7);
            gload_lds16(Bt + (size_t)(n0 + r) * DM + kt + (s << 3),
                        &LB[b][0] + ((i * 512 + w * 64) << 3));
        }
    };
    // stage A stripes: sub=0 -> rows 0-63 & 128-191; sub=1 -> rows 64-127 & 192-255
    auto stA = [&](int kt, int b, int sub) {
#pragma unroll
        for (int i = 0; i < 2; ++i) {
            int c = i * 1024 + sub * 512 + t;
            int r = c >> 3, s = (c & 7) ^ (r & 7);
            gload_lds16(A + (size_t)(m0 + r) * DM + kt + (s << 3),
                        &LA[b][0] + ((i * 1024 + sub * 512 + w * 64) << 3));
        }
    };

    bf16x8 a[8], bq[8];
    f32x4 acc[8][4];
#pragma unroll
    for (int i = 0; i < 8; ++i)
#pragma unroll
        for (int j = 0; j < 4; ++j) acc[i][j] = f32x4{0.f, 0.f, 0.f, 0.f};

    // read A-frags for m-half MH (8 x ds_read_b128, swizzled)
    auto rdA = [&](const u16* base, auto MHt) {
        constexpr int MH = decltype(MHt)::v;
#pragma unroll
        for (int mi = 0; mi < 4; ++mi)
#pragma unroll
            for (int kk = 0; kk < 2; ++kk) {
                int r = wm * 128 + MH * 64 + mi * 16 + r16;
                int bb = (r * 128 + kk * 64 + g4 * 16) ^ ((r & 7) << 4);
                a[mi * 2 + kk] = *(const bf16x8*)((const char*)base + bb);
            }
    };
    // read B-frags for n-half NH (4 x ds_read_b128)
    auto rdB = [&](const u16* base, auto NHt) {
        constexpr int NH_ = decltype(NHt)::v;
#pragma unroll
        for (int ni = 0; ni < 2; ++ni)
#pragma unroll
            for (int kk = 0; kk < 2; ++kk) {
                int r = wn * 64 + (NH_ * 2 + ni) * 16 + r16;
                int bb = (r * 128 + kk * 64 + g4 * 16) ^ ((r & 7) << 4);
                bq[(NH_ * 2 + ni) * 2 + kk] = *(const bf16x8*)((const char*)base + bb);
            }
    };
    // 16 MFMA: quadrant (m-half MH) x (n-half NH), T5 setprio around cluster
    auto mm = [&](auto MHt, auto NHt) {
        constexpr int MH = decltype(MHt)::v;
        constexpr int NH_ = decltype(NHt)::v;
        __builtin_amdgcn_s_setprio(1);
#pragma unroll
        for (int mi = 0; mi < 4; ++mi)
#pragma unroll
            for (int ni = 0; ni < 2; ++ni)
#pragma unroll
                for (int kk = 0; kk < 2; ++kk)
                    mfma16(acc[MH * 4 + mi][NH_ * 2 + ni],
                           a[mi * 2 + kk], bq[(NH_ * 2 + ni) * 2 + kk]);
        __builtin_amdgcn_s_setprio(0);
    };

    // prologue: stage tile 0 into buf 0, full drain (once, outside main loop)
    stB(0, 0); stA(0, 0, 0); stA(0, 0, 1);
    asm volatile("s_waitcnt vmcnt(0)" ::: "memory");
    __builtin_amdgcn_s_barrier();
    asm volatile("" ::: "memory");

    for (int tk = 0; tk < 64; ++tk) {
        const int b = tk & 1;
        const u16* Ab = &LA[b][0];
        const u16* Bb = &LB[b][0];
        const int ktn = (tk + 1) * 64;
        const bool pf = (tk + 1 < 64);

        // ---- P1: reads A-half0 + B-half0; stage next B (4 gloads) ----
        rdA(Ab, ic<0>{}); rdB(Bb, ic<0>{});
        if (pf) stB(ktn, b ^ 1);
        __builtin_amdgcn_s_barrier();
        asm volatile("s_waitcnt lgkmcnt(0)" ::: "memory");
        __builtin_amdgcn_sched_barrier(0);
        mm(ic<0>{}, ic<0>{});
        __builtin_amdgcn_s_barrier();
        asm volatile("" ::: "memory");

        // ---- P2: reads B-half1; stage next A stripes-0 (2 gloads) ----
        rdB(Bb, ic<1>{});
        if (pf) stA(ktn, b ^ 1, 0);
        __builtin_amdgcn_s_barrier();
        asm volatile("s_waitcnt lgkmcnt(0)" ::: "memory");
        __builtin_amdgcn_sched_barrier(0);
        mm(ic<0>{}, ic<1>{});
        asm volatile("s_waitcnt vmcnt(6)" ::: "memory");  // retire prev stripes-1
        __builtin_amdgcn_s_barrier();
        asm volatile("" ::: "memory");

        // ---- P3: reads A-half1; stage next A stripes-1 (2 gloads) ----
        rdA(Ab, ic<1>{});
        if (pf) stA(ktn, b ^ 1, 1);
        __builtin_amdgcn_s_barrier();
        asm volatile("s_waitcnt lgkmcnt(0)" ::: "memory");
        __builtin_amdgcn_sched_barrier(0);
        mm(ic<1>{}, ic<1>{});
        __builtin_amdgcn_s_barrier();
        asm volatile("" ::: "memory");

        // ---- P4: no reads/stages; retire next tile's B + stripes-0 ----
        mm(ic<1>{}, ic<0>{});
        asm volatile("s_waitcnt vmcnt(2)" ::: "memory");
        __builtin_amdgcn_s_barrier();
        asm volatile("" ::: "memory");
    }

    // ---- epilogue ----
    if constexpr (MODE == 0) {
        if (n0 < 5120) {
#pragma unroll
            for (int fi = 0; fi < 8; ++fi)
#pragma unroll
                for (int ni = 0; ni < 4; ++ni) {
                    const int row = m0 + wm * 128 + fi * 16 + g4 * 4;
                    const int col = n0 + wn * 64 + ni * 16 + r16;
#pragma unroll
                    for (int j = 0; j < 4; ++j)
                        Cqk[(size_t)(row + j) * LDQ + col] = f2bf(acc[fi][ni][j]);
                }
        } else {
#pragma unroll
            for (int fi = 0; fi < 8; ++fi)
#pragma unroll
                for (int ni = 0; ni < 4; ++ni) {
                    const int row = m0 + wm * 128 + fi * 16 + g4 * 4;
                    const int col = n0 + wn * 64 + ni * 16 + r16 - 5120;
                    ushort4 v4;
                    v4.x = f2bf(acc[fi][ni][0]); v4.y = f2bf(acc[fi][ni][1]);
                    v4.z = f2bf(acc[fi][ni][2]); v4.w = f2bf(acc[fi][ni][3]);
                    *(ushort4*)&Vt[(size_t)col * S + row] = v4;
                }
        }
    } else {
#pragma unroll
        for (int fi = 0; fi < 8; ++fi)
#pragma unroll
            for (int ni = 0; ni < 4; ++ni) {
                const int row = m0 + wm * 128 + fi * 16 + g4 * 4;
                const int col = n0 + wn * 64 + ni * 16 + r16;
#pragma unroll
                for (int j = 0; j < 4; ++j)
                    Cf[(size_t)(row + j) * DM + col] = acc[fi][ni][j];
            }
    }
}

// ---------------- causal GQA flash attention ----------------
// grid (16, 32): block p handles q-tiles p and 31-p (balanced causal = 33 kv-tiles).
// Q in QK[s][h*128], K in QK[s][4096+kvh*128] (stride 5120; Q pre-scaled by
// log2(e)/sqrt(128)). Vt bf16 [NKV*128][S]. All LDS XOR-swizzled.
__global__ __launch_bounds__(256, 2)
void attn_fwd(const u16* __restrict__ QK, const u16* __restrict__ Vt,
              u16* __restrict__ O) {
    __shared__ u16 Kl[2][64 * 128];
    __shared__ u16 Vl[2][128 * 64];
    __shared__ u16 Pl[4 * 16 * 64];

    const int t = threadIdx.x;
    const int w = t >> 6, l = t & 63;
    const int r16 = l & 15, g4 = l >> 4;
    const int h = blockIdx.y;
    const int kvh = h >> 2;
    const int p = blockIdx.x;
    const int q0A = p * 64, q0B = (31 - p) * 64;
    const int ntA = p + 1, ntB = 32 - p;

    const u16* Kg = QK + 4096 + kvh * HD;
    const u16* Vg = Vt + (size_t)(kvh * HD) * S;
    u16* Pb = &Pl[w * 1024];

    bf16x8 qfA[4], qfB[4];
    {
        const u16* Qg = QK + h * HD;
        const size_t qrA = (size_t)(q0A + w * 16 + r16) * LDQ;
        const size_t qrB = (size_t)(q0B + w * 16 + r16) * LDQ;
#pragma unroll
        for (int kg = 0; kg < 4; ++kg) {
            qfA[kg] = *(const bf16x8*)&Qg[qrA + kg * 32 + g4 * 8];
            qfB[kg] = *(const bf16x8*)&Qg[qrB + kg * 32 + g4 * 8];
        }
    }

    f32x4 accA[8], accB[8];
    float mA[4], lA[4], mB[4], lB[4];
#pragma unroll
    for (int i = 0; i < 8; ++i) { accA[i] = f32x4{0,0,0,0}; accB[i] = f32x4{0,0,0,0}; }
#pragma unroll
    for (int j = 0; j < 4; ++j) { mA[j] = -3.0e38f; lA[j] = 0.f; mB[j] = -3.0e38f; lB[j] = 0.f; }

    auto stage = [&](int tk, int b) {
        const int kv0 = tk * 64;
#pragma unroll
        for (int i = 0; i < 4; ++i) {
            int c = i * 256 + t;
            int r = c >> 4, s = (c & 15) ^ (r & 7);
            gload_lds16(Kg + (size_t)(kv0 + r) * LDQ + (s << 3),
                        &Kl[b][0] + ((i * 256 + w * 64) << 3));
        }
#pragma unroll
        for (int i = 0; i < 4; ++i) {
            int c = i * 256 + t;
            int r = c >> 3, s = (c & 7) ^ (r & 7);
            gload_lds16(Vg + (size_t)r * S + kv0 + (s << 3),
                        &Vl[b][0] + ((i * 256 + w * 64) << 3));
        }
    };

    auto compute = [&](f32x4 (&acco)[8], float (&mrun)[4], float (&lrun)[4],
                       const bf16x8 (&qf)[4], int q0, int tk, bool maskit, int b) {
        const int kv0 = tk * 64;
        const u16* Kb = &Kl[b][0];
        const u16* Vb = &Vl[b][0];

        f32x4 sc[4];
#pragma unroll
        for (int ni = 0; ni < 4; ++ni) sc[ni] = f32x4{0,0,0,0};
        __builtin_amdgcn_s_setprio(1);
#pragma unroll
        for (int kg = 0; kg < 4; ++kg) {
#pragma unroll
            for (int ni = 0; ni < 4; ++ni) {
                int row = ni * 16 + r16;
                int bb = (row * 256 + kg * 64 + g4 * 16) ^ ((row & 7) << 4);
                bf16x8 kf = *(const bf16x8*)((const char*)Kb + bb);
                mfma16(sc[ni], qf[kg], kf);
            }
        }
        __builtin_amdgcn_s_setprio(0);

        float vmax[4];
        bool grow = false;
#pragma unroll
        for (int j = 0; j < 4; ++j) {
            if (maskit) {
                const int qg = q0 + w * 16 + g4 * 4 + j;
#pragma unroll
                for (int ni = 0; ni < 4; ++ni)
                    if (kv0 + ni * 16 + r16 > qg) sc[ni][j] = -3.0e38f;
            }
            float v = fmaxf(fmaxf(sc[0][j], sc[1][j]), fmaxf(sc[2][j], sc[3][j]));
            v = fmaxf(v, __shfl_xor(v, 1, 16));
            v = fmaxf(v, __shfl_xor(v, 2, 16));
            v = fmaxf(v, __shfl_xor(v, 4, 16));
            v = fmaxf(v, __shfl_xor(v, 8, 16));
            vmax[j] = v;
            grow = grow || (v > mrun[j] + 11.5f);
        }
        float fac[4] = {1.f, 1.f, 1.f, 1.f};
        if (__any(grow)) {
#pragma unroll
            for (int j = 0; j < 4; ++j) {
                float nm = fmaxf(mrun[j], vmax[j]);
                fac[j] = exp2f(mrun[j] - nm);
                mrun[j] = nm;
            }
#pragma unroll
            for (int i = 0; i < 8; ++i)
#pragma unroll
                for (int j = 0; j < 4; ++j) acco[i][j] *= fac[j];
        }
#pragma unroll
        for (int j = 0; j < 4; ++j) {
            float p0 = exp2f(sc[0][j] - mrun[j]);
            float p1 = exp2f(sc[1][j] - mrun[j]);
            float p2 = exp2f(sc[2][j] - mrun[j]);
            float p3 = exp2f(sc[3][j] - mrun[j]);
            sc[0][j] = p0; sc[1][j] = p1; sc[2][j] = p2; sc[3][j] = p3;
            float s2 = (p0 + p1) + (p2 + p3);
            s2 += __shfl_xor(s2, 1, 16);
            s2 += __shfl_xor(s2, 2, 16);
            s2 += __shfl_xor(s2, 4, 16);
            s2 += __shfl_xor(s2, 8, 16);
            lrun[j] = lrun[j] * fac[j] + s2;
        }

#pragma unroll
        for (int ni = 0; ni < 4; ++ni)
#pragma unroll
            for (int j = 0; j < 4; ++j) {
                int row = g4 * 4 + j;
                int bb = (row * 128 + ((ni * 16 + r16) << 1)) ^ ((row & 7) << 4);
                *(u16*)((char*)Pb + bb) = f2bf(sc[ni][j]);
            }
        asm volatile("s_waitcnt lgkmcnt(0)" ::: "memory");
        __builtin_amdgcn_sched_barrier(0);

        int pb0 = (r16 * 128 + g4 * 16) ^ ((r16 & 7) << 4);
        bf16x8 pf0 = *(const bf16x8*)((const char*)Pb + pb0);
        bf16x8 pf1 = *(const bf16x8*)((const char*)Pb + (pb0 ^ 64));
        __builtin_amdgcn_s_setprio(1);
#pragma unroll
        for (int ni = 0; ni < 8; ++ni) {
            int row = ni * 16 + r16;
            int bb = (row * 128 + g4 * 16) ^ ((row & 7) << 4);
            bf16x8 v0 = *(const bf16x8*)((const char*)Vb + bb);
            mfma16(acco[ni], pf0, v0);
            bf16x8 v1 = *(const bf16x8*)((const char*)Vb + (bb ^ 64));
            mfma16(acco[ni], pf1, v1);
        }
        __builtin_amdgcn_s_setprio(0);
    };

    auto epilogue = [&](f32x4 (&acco)[8], float (&lrun)[4], int q0) {
        float rl[4];
#pragma unroll
        for (int j = 0; j < 4; ++j) rl[j] = 1.0f / lrun[j];
#pragma unroll
        for (int ni = 0; ni < 8; ++ni)
#pragma unroll
            for (int j = 0; j < 4; ++j) {
                const int qg = q0 + w * 16 + g4 * 4 + j;
                O[(size_t)qg * DM + h * HD + ni * 16 + r16] = f2bf(acco[ni][j] * rl[j]);
            }
    };

    stage(0, 0);
    asm volatile("s_waitcnt vmcnt(0)" ::: "memory");
    __syncthreads();
    int buf = 0;

    for (int tk = 0; tk < ntA; ++tk) {
        if (tk + 1 < ntA) stage(tk + 1, buf ^ 1);
        else              stage(0, buf ^ 1);
        compute(accA, mA, lA, qfA, q0A, tk, tk == ntA - 1, buf);
        asm volatile("s_waitcnt vmcnt(0)" ::: "memory");
        __syncthreads();
        buf ^= 1;
    }
    epilogue(accA, lA, q0A);

    for (int tk = 0; tk < ntB; ++tk) {
        if (tk + 1 < ntB) stage(tk + 1, buf ^ 1);
        compute(accB, mB, lB, qfB, q0B, tk, tk == ntB - 1, buf);
        asm volatile("s_waitcnt vmcnt(0)" ::: "memory");
        __syncthreads();
        buf ^= 1;
    }
    epilogue(accB, lB, q0B);
}

// ---------------- launch ----------------
extern "C" void kernel_launch(void* const* d_in, const int* in_sizes, int n_in,
                              void* d_out, int out_size, void* d_ws, size_t ws_size,
                              hipStream_t stream) {
    const float* X  = (const float*)d_in[0];
    // d_in[1] = position_ids (arange(S) by construction)
    const float* Wq = (const float*)d_in[2];
    const float* Wk = (const float*)d_in[3];
    const float* Wv = (const float*)d_in[4];
    const float* Wo = (const float*)d_in[5];

    char* ws = (char*)d_ws;
    u16*    Xbf  = (u16*)(ws + 0);            // 2048x4096 bf16 = 16,777,216
    u16*    Wqkv = (u16*)(ws + 16777216);     // 6144x4096 bf16 = 50,331,648
    u16*    Wobf = (u16*)(ws + 67108864);     // 4096x4096 bf16 = 33,554,432
    u16*    QKb  = (u16*)(ws + 100663296);    // 2048x5120 bf16 = 20,971,520
    u16*    Vtbf = (u16*)(ws + 121634816);    // 1024x2048 bf16 =  4,194,304 (V^T)
    u16*    Obf  = (u16*)(ws + 125829120);    // 2048x4096 bf16 = 16,777,216
    float2* tbl  = (float2*)(ws + 142606336); // 2048x64 float2 =  1,048,576
    if (ws_size < 143654912ull) return;

    dim3 blk(256);

    cvt_kernel<<<2048, blk, 0, stream>>>(X,  Xbf,  S * DM / 4);
    cvt_qkv<<<2048, blk, 0, stream>>>(Wq, Wk, Wv, Wqkv);
    cvt_kernel<<<2048, blk, 0, stream>>>(Wo, Wobf, DM * DM / 4);
    rope_table_kernel<<<(S * 64 + 255) / 256, blk, 0, stream>>>(tbl);

    // fused QKV projection: 256^2 8-phase, grid 8x24 = 192 blocks
    gemm8<0, 24><<<dim3(192), dim3(512), 0, stream>>>(Xbf, Wqkv, QKb, Vtbf, nullptr);

    // RoPE; Q folds in log2(e)*HD^-0.5 so softmax runs in exp2 domain
    rope_kernel<<<(S * NH * 64 + 255) / 256, blk, 0, stream>>>(
        QKb, tbl, NH, LDQ, 0.08838834764831845f * 1.4426950408889634f);
    rope_kernel<<<(S * NKV * 64 + 255) / 256, blk, 0, stream>>>(
        QKb + 4096, tbl, NKV, LDQ, 1.0f);

    attn_fwd<<<dim3(16, NH), blk, 0, stream>>>(QKb, Vtbf, Obf);

    // output projection -> fp32: 256^2 8-phase, grid 8x16 = 128 blocks
    gemm8<1, 16><<<dim3(128), dim3(512), 0, stream>>>(Obf, Wobf, nullptr, nullptr,
                                                      (float*)d_out);
}

// Round 4
// 394.234 us; speedup vs baseline: 1.1402x; 1.1402x over previous
//
#include <hip/hip_runtime.h>
#include <stdint.h>

typedef unsigned short u16;
typedef __attribute__((ext_vector_type(4))) float f32x4;
typedef __attribute__((ext_vector_type(8))) short bf16x8;

static constexpr int S   = 2048;
static constexpr int DM  = 4096;  // model dim
static constexpr int NH  = 32;    // query heads
static constexpr int NKV = 8;     // kv heads
static constexpr int HD  = 128;   // head dim
static constexpr int LDQ = 5120;  // QK buffer row stride (Q 4096 | K 1024)

template<int V> struct ic { static constexpr int v = V; };

__device__ __forceinline__ u16 f2bf(float f) {
    union { float f; unsigned u; } v; v.f = f;
    return (u16)((v.u + 0x7FFFu + ((v.u >> 16) & 1u)) >> 16);
}
__device__ __forceinline__ float bf2f(u16 h) {
    union { unsigned u; float f; } v; v.u = ((unsigned)h) << 16;
    return v.f;
}

__device__ __forceinline__ void mfma16(f32x4& d, bf16x8 a, bf16x8 b) {
    asm("v_mfma_f32_16x16x32_bf16 %0, %1, %2, %0" : "+v"(d) : "v"(a), "v"(b));
}

// async global->LDS, 16B/lane. LDS base is wave-uniform; HW adds lane*16.
__device__ __forceinline__ void gload_lds16(const u16* g, u16* lds) {
    __builtin_amdgcn_global_load_lds((__attribute__((address_space(1))) void*)g,
                                     (__attribute__((address_space(3))) void*)lds,
                                     16, 0, 0);
}

// ---------------- fp32 -> bf16 converts ----------------
__global__ __launch_bounds__(256) void cvt_kernel(const float* __restrict__ in,
                                                  u16* __restrict__ out, int n4) {
    int i = blockIdx.x * blockDim.x + threadIdx.x;
    int stride = gridDim.x * blockDim.x;
    for (; i < n4; i += stride) {
        float4 v = ((const float4*)in)[i];
        ushort4 o;
        o.x = f2bf(v.x); o.y = f2bf(v.y); o.z = f2bf(v.z); o.w = f2bf(v.w);
        ((ushort4*)out)[i] = o;
    }
}

// fused Wq|Wk|Wv -> contiguous bf16 [6144][4096]
__global__ __launch_bounds__(256) void cvt_qkv(const float* __restrict__ Wq,
                                               const float* __restrict__ Wk,
                                               const float* __restrict__ Wv,
                                               u16* __restrict__ out) {
    const int n4 = 6144 * 4096 / 4;
    int i = blockIdx.x * blockDim.x + threadIdx.x;
    int stride = gridDim.x * blockDim.x;
    for (; i < n4; i += stride) {
        float4 v;
        if (i < 4194304)       v = ((const float4*)Wq)[i];
        else if (i < 5242880)  v = ((const float4*)Wk)[i - 4194304];
        else                   v = ((const float4*)Wv)[i - 5242880];
        ushort4 o;
        o.x = f2bf(v.x); o.y = f2bf(v.y); o.z = f2bf(v.z); o.w = f2bf(v.w);
        ((ushort4*)out)[i] = o;
    }
}

// ---------------- split-K reduce: out = a + b (f32) ----------------
__global__ __launch_bounds__(256) void add2_kernel(const float* __restrict__ a,
                                                   const float* __restrict__ b,
                                                   float* __restrict__ o, int n4) {
    int i = blockIdx.x * blockDim.x + threadIdx.x;
    int st = gridDim.x * blockDim.x;
    for (; i < n4; i += st) {
        float4 x = ((const float4*)a)[i];
        float4 y = ((const float4*)b)[i];
        x.x += y.x; x.y += y.y; x.z += y.z; x.w += y.w;
        ((float4*)o)[i] = x;
    }
}

// ---------------- RoPE cos/sin table ----------------
__global__ __launch_bounds__(256) void rope_table_kernel(float2* __restrict__ tbl) {
    int i = blockIdx.x * blockDim.x + threadIdx.x;
    if (i >= S * 64) return;
    int p = i >> 6, j = i & 63;
    float inv = powf(10000.0f, -(float)j / 64.0f);
    float a = (float)p * inv;
    tbl[i] = make_float2(cosf(a), sinf(a));
}

// ---------------- RoPE in-place on bf16, row stride ld, pair (d, d+64) ----------------
__global__ __launch_bounds__(256) void rope_kernel(u16* __restrict__ X,
                                                   const float2* __restrict__ tbl,
                                                   int nh, int ld, float scale) {
    int i = blockIdx.x * blockDim.x + threadIdx.x;
    int total = S * nh * 64;
    if (i >= total) return;
    int dd = i & 63;
    int t2 = i >> 6;
    int hh = t2 % nh;
    int s  = t2 / nh;
    size_t base = (size_t)s * ld + (size_t)hh * HD + dd;
    float x1 = bf2f(X[base]);
    float x2 = bf2f(X[base + 64]);
    float2 cs = tbl[(s << 6) + dd];
    X[base]      = f2bf((x1 * cs.x - x2 * cs.y) * scale);
    X[base + 64] = f2bf((x2 * cs.x + x1 * cs.y) * scale);
}

// ======================= 256x256 8-phase GEMM v2 (8 waves, BK=64) =======================
// C = A(2048 x K) * Bt(N x K)^T.  KT K-tiles of 64.
// MODE 0: QKV epilogue (n<5120 -> Cqk bf16 stride LDQ; else Vt[n-5120][m] bf16)
// MODE 2: f32 partial, split-K=2 (kslice = blockIdx.x&1, k0 = kslice*KT*64),
//         written to Cf + kslice*S*DM.
// Half-tile staggered staging: quadrants (0,0),(0,1),(1,1),(1,0); slots free
// A0/B0 after ph1, B1 after ph2, A1 after ph3. Stage queue: ph1->B1(t+1),
// ph2->A1(t+1), ph3->A0(t+2), ph4->B0(t+2). Uniform vmcnt(8) per phase end
// retires exactly the half needed next (>=4-phase flight per load); peeled
// tail waits 4/2/0. LDS XOR-swizzled (byte ^= (row&7)<<4), inverse on source.
template<int MODE, int NBX, int KT>
__global__ __launch_bounds__(512, 2)
void gemm8(const u16* __restrict__ A, const u16* __restrict__ Bt,
           u16* __restrict__ Cqk, u16* __restrict__ Vt, float* __restrict__ Cf) {
    __shared__ u16 LA[2][256 * 64];
    __shared__ u16 LB[2][256 * 64];
    const int t = threadIdx.x;
    const int w = t >> 6, l = t & 63;
    const int r16 = l & 15, g4 = l >> 4;
    const int wm = w >> 2, wn = w & 3;

    int id = blockIdx.x;
    int k0 = 0;
    if constexpr (MODE == 2) {
        k0 = (id & 1) * (KT * 64);
        Cf += (size_t)(id & 1) * S * DM;
        id >>= 1;
    }
    // T1 XCD swizzle (bijective: grid/2^? is a multiple of 8)
    const int sw = (id & 7) * NBX + (id >> 3);
    const int bx = sw % NBX, by = sw / NBX;
    const int m0 = by * 256, n0 = bx * 256;

    // stage A half h (rows h*64+[0,64) and 128+h*64+[0,64)), 2 gloads
    auto stA = [&](int kt, int b, int h) {
#pragma unroll
        for (int i = 0; i < 2; ++i) {
            int cc = i * 512 + t;
            int rh = cc >> 3, q = cc & 7;
            int row = (rh >> 6) * 128 + h * 64 + (rh & 63);
            int s = q ^ (row & 7);
            int rh0 = i * 64 + w * 8;
            int row0 = (rh0 >> 6) * 128 + h * 64 + (rh0 & 63);
            gload_lds16(A + (size_t)(m0 + row) * DM + kt + (s << 3),
                        &LA[b][0] + (row0 << 6));
        }
    };
    // stage B half h (rows ≡ h*32+[0,32) mod 64), 2 gloads
    auto stB = [&](int kt, int b, int h) {
#pragma unroll
        for (int i = 0; i < 2; ++i) {
            int cc = i * 512 + t;
            int rh = cc >> 3, q = cc & 7;
            int row = (rh >> 5) * 64 + h * 32 + (rh & 31);
            int s = q ^ (row & 7);
            int rh0 = i * 64 + w * 8;
            int row0 = (rh0 >> 5) * 64 + h * 32 + (rh0 & 31);
            gload_lds16(Bt + (size_t)(n0 + row) * DM + kt + (s << 3),
                        &LB[b][0] + (row0 << 6));
        }
    };

    bf16x8 a[8], b0[4], b1[4];
    f32x4 acc[8][4];
#pragma unroll
    for (int i = 0; i < 8; ++i)
#pragma unroll
        for (int j = 0; j < 4; ++j) acc[i][j] = f32x4{0.f, 0.f, 0.f, 0.f};

    auto rdA = [&](const u16* base, auto MHt) {
        constexpr int MH = decltype(MHt)::v;
#pragma unroll
        for (int mi = 0; mi < 4; ++mi)
#pragma unroll
            for (int kk = 0; kk < 2; ++kk) {
                int r = wm * 128 + MH * 64 + mi * 16 + r16;
                int bb = (r * 128 + kk * 64 + g4 * 16) ^ ((r & 7) << 4);
                a[mi * 2 + kk] = *(const bf16x8*)((const char*)base + bb);
            }
    };
    auto rdB = [&](const u16* base, auto NHt, bf16x8 (&bq)[4]) {
        constexpr int NH_ = decltype(NHt)::v;
#pragma unroll
        for (int ni = 0; ni < 2; ++ni)
#pragma unroll
            for (int kk = 0; kk < 2; ++kk) {
                int r = wn * 64 + (NH_ * 2 + ni) * 16 + r16;
                int bb = (r * 128 + kk * 64 + g4 * 16) ^ ((r & 7) << 4);
                bq[ni * 2 + kk] = *(const bf16x8*)((const char*)base + bb);
            }
    };
    auto mm = [&](bf16x8 (&bq)[4], auto MHt, auto NHt) {
        constexpr int MH = decltype(MHt)::v;
        constexpr int NH_ = decltype(NHt)::v;
        __builtin_amdgcn_s_setprio(1);
#pragma unroll
        for (int mi = 0; mi < 4; ++mi)
#pragma unroll
            for (int ni = 0; ni < 2; ++ni)
#pragma unroll
                for (int kk = 0; kk < 2; ++kk)
                    mfma16(acc[MH * 4 + mi][NH_ * 2 + ni],
                           a[mi * 2 + kk], bq[ni * 2 + kk]);
        __builtin_amdgcn_s_setprio(0);
    };

    // prologue: A0(0),B0(0),B1(0),A1(0),A0(1),B0(1) then retire first two
    stA(k0, 0, 0);
    stB(k0, 0, 0);
    stB(k0, 0, 1);
    stA(k0, 0, 1);
    stA(k0 + 64, 1, 0);
    stB(k0 + 64, 1, 0);
    asm volatile("s_waitcnt vmcnt(8)" ::: "memory");
    __builtin_amdgcn_s_barrier();

    for (int tk = 0; tk < KT; ++tk) {
        const int b = tk & 1;
        const u16* Ab = &LA[b][0];
        const u16* Bb = &LB[b][0];
        const int kt1 = k0 + (tk + 1) * 64;
        const int kt2 = k0 + (tk + 2) * 64;

        // ---- ph1: read A0,B0; stage B1(t+1) ----
        rdA(Ab, ic<0>{});
        rdB(Bb, ic<0>{}, b0);
        if (tk + 1 < KT) stB(kt1, b ^ 1, 1);
        __builtin_amdgcn_s_barrier();
        asm volatile("s_waitcnt lgkmcnt(0)" ::: "memory");
        __builtin_amdgcn_sched_barrier(0);
        mm(b0, ic<0>{}, ic<0>{});
        if (tk == KT - 1) asm volatile("s_waitcnt vmcnt(2)" ::: "memory");
        else              asm volatile("s_waitcnt vmcnt(8)" ::: "memory");
        __builtin_amdgcn_s_barrier();

        // ---- ph2: read B1; stage A1(t+1) ----
        rdB(Bb, ic<1>{}, b1);
        if (tk + 1 < KT) stA(kt1, b ^ 1, 1);
        __builtin_amdgcn_s_barrier();
        asm volatile("s_waitcnt lgkmcnt(0)" ::: "memory");
        __builtin_amdgcn_sched_barrier(0);
        mm(b1, ic<0>{}, ic<1>{});
        if (tk == KT - 1) asm volatile("s_waitcnt vmcnt(0)" ::: "memory");
        else              asm volatile("s_waitcnt vmcnt(8)" ::: "memory");
        __builtin_amdgcn_s_barrier();

        // ---- ph3: read A1; stage A0(t+2) ----
        rdA(Ab, ic<1>{});
        if (tk + 2 < KT) stA(kt2, b, 0);
        __builtin_amdgcn_s_barrier();
        asm volatile("s_waitcnt lgkmcnt(0)" ::: "memory");
        __builtin_amdgcn_sched_barrier(0);
        mm(b1, ic<1>{}, ic<1>{});
        asm volatile("s_waitcnt vmcnt(8)" ::: "memory");
        __builtin_amdgcn_s_barrier();

        // ---- ph4: stage B0(t+2); mm uses regs only ----
        if (tk + 2 < KT) stB(kt2, b, 0);
        mm(b0, ic<1>{}, ic<0>{});
        if (tk == KT - 2)      asm volatile("s_waitcnt vmcnt(4)" ::: "memory");
        else if (tk == KT - 1) asm volatile("s_waitcnt vmcnt(0)" ::: "memory");
        else                   asm volatile("s_waitcnt vmcnt(8)" ::: "memory");
        __builtin_amdgcn_s_barrier();
    }

    // ---- epilogue ----
    if constexpr (MODE == 0) {
        if (n0 < 5120) {
#pragma unroll
            for (int fi = 0; fi < 8; ++fi)
#pragma unroll
                for (int ni = 0; ni < 4; ++ni) {
                    const int row = m0 + wm * 128 + fi * 16 + g4 * 4;
                    const int col = n0 + wn * 64 + ni * 16 + r16;
#pragma unroll
                    for (int j = 0; j < 4; ++j)
                        Cqk[(size_t)(row + j) * LDQ + col] = f2bf(acc[fi][ni][j]);
                }
        } else {
#pragma unroll
            for (int fi = 0; fi < 8; ++fi)
#pragma unroll
                for (int ni = 0; ni < 4; ++ni) {
                    const int row = m0 + wm * 128 + fi * 16 + g4 * 4;
                    const int col = n0 + wn * 64 + ni * 16 + r16 - 5120;
                    ushort4 v4;
                    v4.x = f2bf(acc[fi][ni][0]); v4.y = f2bf(acc[fi][ni][1]);
                    v4.z = f2bf(acc[fi][ni][2]); v4.w = f2bf(acc[fi][ni][3]);
                    *(ushort4*)&Vt[(size_t)col * S + row] = v4;
                }
        }
    } else {
#pragma unroll
        for (int fi = 0; fi < 8; ++fi)
#pragma unroll
            for (int ni = 0; ni < 4; ++ni) {
                const int row = m0 + wm * 128 + fi * 16 + g4 * 4;
                const int col = n0 + wn * 64 + ni * 16 + r16;
#pragma unroll
                for (int j = 0; j < 4; ++j)
                    Cf[(size_t)(row + j) * DM + col] = acc[fi][ni][j];
            }
    }
}

// ---------------- causal GQA flash attention ----------------
// grid (16, 32): block p handles q-tiles p and 31-p. MERGED loop: tile B's kv
// range [0, 32-p) is a superset of A's [0, p+1) -> one stage serves both
// computes. Q pre-scaled by log2(e)/sqrt(128) (exp2-domain softmax).
// Vt bf16 [NKV*128][S]. All LDS XOR-swizzled.
__global__ __launch_bounds__(256, 2)
void attn_fwd(const u16* __restrict__ QK, const u16* __restrict__ Vt,
              u16* __restrict__ O) {
    __shared__ u16 Kl[2][64 * 128];
    __shared__ u16 Vl[2][128 * 64];
    __shared__ u16 Pl[4 * 16 * 64];

    const int t = threadIdx.x;
    const int w = t >> 6, l = t & 63;
    const int r16 = l & 15, g4 = l >> 4;
    const int h = blockIdx.y;
    const int kvh = h >> 2;
    const int p = blockIdx.x;
    const int q0A = p * 64, q0B = (31 - p) * 64;
    const int ntA = p + 1, ntB = 32 - p;   // ntA <= ntB

    const u16* Kg = QK + 4096 + kvh * HD;
    const u16* Vg = Vt + (size_t)(kvh * HD) * S;
    u16* Pb = &Pl[w * 1024];

    bf16x8 qfA[4], qfB[4];
    {
        const u16* Qg = QK + h * HD;
        const size_t qrA = (size_t)(q0A + w * 16 + r16) * LDQ;
        const size_t qrB = (size_t)(q0B + w * 16 + r16) * LDQ;
#pragma unroll
        for (int kg = 0; kg < 4; ++kg) {
            qfA[kg] = *(const bf16x8*)&Qg[qrA + kg * 32 + g4 * 8];
            qfB[kg] = *(const bf16x8*)&Qg[qrB + kg * 32 + g4 * 8];
        }
    }

    f32x4 accA[8], accB[8];
    float mA[4], lA[4], mB[4], lB[4];
#pragma unroll
    for (int i = 0; i < 8; ++i) { accA[i] = f32x4{0,0,0,0}; accB[i] = f32x4{0,0,0,0}; }
#pragma unroll
    for (int j = 0; j < 4; ++j) { mA[j] = -3.0e38f; lA[j] = 0.f; mB[j] = -3.0e38f; lB[j] = 0.f; }

    auto stage = [&](int tk, int b) {
        const int kv0 = tk * 64;
#pragma unroll
        for (int i = 0; i < 4; ++i) {
            int c = i * 256 + t;
            int r = c >> 4, s = (c & 15) ^ (r & 7);
            gload_lds16(Kg + (size_t)(kv0 + r) * LDQ + (s << 3),
                        &Kl[b][0] + ((i * 256 + w * 64) << 3));
        }
#pragma unroll
        for (int i = 0; i < 4; ++i) {
            int c = i * 256 + t;
            int r = c >> 3, s = (c & 7) ^ (r & 7);
            gload_lds16(Vg + (size_t)r * S + kv0 + (s << 3),
                        &Vl[b][0] + ((i * 256 + w * 64) << 3));
        }
    };

    auto compute = [&](f32x4 (&acco)[8], float (&mrun)[4], float (&lrun)[4],
                       const bf16x8 (&qf)[4], int q0, int tk, bool maskit, int b) {
        const int kv0 = tk * 64;
        const u16* Kb = &Kl[b][0];
        const u16* Vb = &Vl[b][0];

        f32x4 sc[4];
#pragma unroll
        for (int ni = 0; ni < 4; ++ni) sc[ni] = f32x4{0,0,0,0};
        __builtin_amdgcn_s_setprio(1);
#pragma unroll
        for (int kg = 0; kg < 4; ++kg) {
#pragma unroll
            for (int ni = 0; ni < 4; ++ni) {
                int row = ni * 16 + r16;
                int bb = (row * 256 + kg * 64 + g4 * 16) ^ ((row & 7) << 4);
                bf16x8 kf = *(const bf16x8*)((const char*)Kb + bb);
                mfma16(sc[ni], qf[kg], kf);
            }
        }
        __builtin_amdgcn_s_setprio(0);

        float vmax[4];
        bool grow = false;
#pragma unroll
        for (int j = 0; j < 4; ++j) {
            if (maskit) {
                const int qg = q0 + w * 16 + g4 * 4 + j;
#pragma unroll
                for (int ni = 0; ni < 4; ++ni)
                    if (kv0 + ni * 16 + r16 > qg) sc[ni][j] = -3.0e38f;
            }
            float v = fmaxf(fmaxf(sc[0][j], sc[1][j]), fmaxf(sc[2][j], sc[3][j]));
            v = fmaxf(v, __shfl_xor(v, 1, 16));
            v = fmaxf(v, __shfl_xor(v, 2, 16));
            v = fmaxf(v, __shfl_xor(v, 4, 16));
            v = fmaxf(v, __shfl_xor(v, 8, 16));
            vmax[j] = v;
            grow = grow || (v > mrun[j] + 11.5f);
        }
        float fac[4] = {1.f, 1.f, 1.f, 1.f};
        if (__any(grow)) {
#pragma unroll
            for (int j = 0; j < 4; ++j) {
                float nm = fmaxf(mrun[j], vmax[j]);
                fac[j] = exp2f(mrun[j] - nm);
                mrun[j] = nm;
            }
#pragma unroll
            for (int i = 0; i < 8; ++i)
#pragma unroll
                for (int j = 0; j < 4; ++j) acco[i][j] *= fac[j];
        }
#pragma unroll
        for (int j = 0; j < 4; ++j) {
            float p0 = exp2f(sc[0][j] - mrun[j]);
            float p1 = exp2f(sc[1][j] - mrun[j]);
            float p2 = exp2f(sc[2][j] - mrun[j]);
            float p3 = exp2f(sc[3][j] - mrun[j]);
            sc[0][j] = p0; sc[1][j] = p1; sc[2][j] = p2; sc[3][j] = p3;
            float s2 = (p0 + p1) + (p2 + p3);
            s2 += __shfl_xor(s2, 1, 16);
            s2 += __shfl_xor(s2, 2, 16);
            s2 += __shfl_xor(s2, 4, 16);
            s2 += __shfl_xor(s2, 8, 16);
            lrun[j] = lrun[j] * fac[j] + s2;
        }

#pragma unroll
        for (int ni = 0; ni < 4; ++ni)
#pragma unroll
            for (int j = 0; j < 4; ++j) {
                int row = g4 * 4 + j;
                int bb = (row * 128 + ((ni * 16 + r16) << 1)) ^ ((row & 7) << 4);
                *(u16*)((char*)Pb + bb) = f2bf(sc[ni][j]);
            }
        asm volatile("s_waitcnt lgkmcnt(0)" ::: "memory");
        __builtin_amdgcn_sched_barrier(0);

        int pb0 = (r16 * 128 + g4 * 16) ^ ((r16 & 7) << 4);
        bf16x8 pf0 = *(const bf16x8*)((const char*)Pb + pb0);
        bf16x8 pf1 = *(const bf16x8*)((const char*)Pb + (pb0 ^ 64));
        __builtin_amdgcn_s_setprio(1);
#pragma unroll
        for (int ni = 0; ni < 8; ++ni) {
            int row = ni * 16 + r16;
            int bb = (row * 128 + g4 * 16) ^ ((row & 7) << 4);
            bf16x8 v0 = *(const bf16x8*)((const char*)Vb + bb);
            mfma16(acco[ni], pf0, v0);
            bf16x8 v1 = *(const bf16x8*)((const char*)Vb + (bb ^ 64));
            mfma16(acco[ni], pf1, v1);
        }
        __builtin_amdgcn_s_setprio(0);
    };

    auto epilogue = [&](f32x4 (&acco)[8], float (&lrun)[4], int q0) {
        float rl[4];
#pragma unroll
        for (int j = 0; j < 4; ++j) rl[j] = 1.0f / lrun[j];
#pragma unroll
        for (int ni = 0; ni < 8; ++ni)
#pragma unroll
            for (int j = 0; j < 4; ++j) {
                const int qg = q0 + w * 16 + g4 * 4 + j;
                O[(size_t)qg * DM + h * HD + ni * 16 + r16] = f2bf(acco[ni][j] * rl[j]);
            }
    };

    stage(0, 0);
    asm volatile("s_waitcnt vmcnt(0)" ::: "memory");
    __syncthreads();
    int buf = 0;

    for (int tk = 0; tk < ntB; ++tk) {
        if (tk + 1 < ntB) stage(tk + 1, buf ^ 1);
        compute(accB, mB, lB, qfB, q0B, tk, tk == ntB - 1, buf);
        if (tk < ntA) compute(accA, mA, lA, qfA, q0A, tk, tk == ntA - 1, buf);
        asm volatile("s_waitcnt vmcnt(0)" ::: "memory");
        __syncthreads();
        buf ^= 1;
    }
    epilogue(accA, lA, q0A);
    epilogue(accB, lB, q0B);
}

// ---------------- launch ----------------
extern "C" void kernel_launch(void* const* d_in, const int* in_sizes, int n_in,
                              void* d_out, int out_size, void* d_ws, size_t ws_size,
                              hipStream_t stream) {
    const float* X  = (const float*)d_in[0];
    // d_in[1] = position_ids (arange(S) by construction)
    const float* Wq = (const float*)d_in[2];
    const float* Wk = (const float*)d_in[3];
    const float* Wv = (const float*)d_in[4];
    const float* Wo = (const float*)d_in[5];

    char* ws = (char*)d_ws;
    u16*    Xbf  = (u16*)(ws + 0);            // 2048x4096 bf16 = 16,777,216
    u16*    Wqkv = (u16*)(ws + 16777216);     // 6144x4096 bf16 = 50,331,648
    u16*    Wobf = (u16*)(ws + 67108864);     // 4096x4096 bf16 = 33,554,432
    u16*    QKb  = (u16*)(ws + 100663296);    // 2048x5120 bf16 = 20,971,520
    u16*    Vtbf = (u16*)(ws + 121634816);    // 1024x2048 bf16 =  4,194,304 (V^T)
    u16*    Obf  = (u16*)(ws + 125829120);    // 2048x4096 bf16 = 16,777,216
    float2* tbl  = (float2*)(ws + 142606336); // 2048x64 float2 =  1,048,576
    // split-K partials (2 x 2048x4096 f32 = 67,108,864) reuse the Xbf+Wqkv
    // region [0, 67108864) -- both are dead before the O-projection runs.
    float*  part = (float*)(ws + 0);
    if (ws_size < 143654912ull) return;

    dim3 blk(256);

    cvt_kernel<<<2048, blk, 0, stream>>>(X,  Xbf,  S * DM / 4);
    cvt_qkv<<<2048, blk, 0, stream>>>(Wq, Wk, Wv, Wqkv);
    cvt_kernel<<<2048, blk, 0, stream>>>(Wo, Wobf, DM * DM / 4);
    rope_table_kernel<<<(S * 64 + 255) / 256, blk, 0, stream>>>(tbl);

    // fused QKV projection: 256^2 8-phase v2, grid 8x24 = 192 blocks
    gemm8<0, 24, 64><<<dim3(192), dim3(512), 0, stream>>>(Xbf, Wqkv, QKb, Vtbf, nullptr);

    // RoPE; Q folds in log2(e)*HD^-0.5 so softmax runs in exp2 domain
    rope_kernel<<<(S * NH * 64 + 255) / 256, blk, 0, stream>>>(
        QKb, tbl, NH, LDQ, 0.08838834764831845f * 1.4426950408889634f);
    rope_kernel<<<(S * NKV * 64 + 255) / 256, blk, 0, stream>>>(
        QKb + 4096, tbl, NKV, LDQ, 1.0f);

    attn_fwd<<<dim3(16, NH), blk, 0, stream>>>(QKb, Vtbf, Obf);

    // output projection, split-K=2: 256 blocks (full chip), f32 partials
    gemm8<2, 16, 32><<<dim3(256), dim3(512), 0, stream>>>(Obf, Wobf, nullptr, nullptr,
                                                          part);
    add2_kernel<<<2048, blk, 0, stream>>>(part, part + (size_t)S * DM,
                                          (float*)d_out, S * DM / 4);
}

// Round 5
// 358.216 us; speedup vs baseline: 1.2549x; 1.1005x over previous
//
#include <hip/hip_runtime.h>
#include <stdint.h>

typedef unsigned short u16;
typedef __attribute__((ext_vector_type(4))) float f32x4;
typedef __attribute__((ext_vector_type(8))) short bf16x8;

static constexpr int S   = 2048;
static constexpr int DM  = 4096;  // model dim
static constexpr int NH  = 32;    // query heads
static constexpr int NKV = 8;     // kv heads
static constexpr int HD  = 128;   // head dim
static constexpr int LDQ = 5120;  // QK buffer row stride (Q 4096 | K 1024)

__device__ __forceinline__ u16 f2bf(float f) {
    union { float f; unsigned u; } v; v.f = f;
    return (u16)((v.u + 0x7FFFu + ((v.u >> 16) & 1u)) >> 16);
}
__device__ __forceinline__ float bf2f(u16 h) {
    union { unsigned u; float f; } v; v.u = ((unsigned)h) << 16;
    return v.f;
}

__device__ __forceinline__ void mfma16(f32x4& d, bf16x8 a, bf16x8 b) {
    asm("v_mfma_f32_16x16x32_bf16 %0, %1, %2, %0" : "+v"(d) : "v"(a), "v"(b));
}

// async global->LDS, 16B/lane. LDS base is wave-uniform; HW adds lane*16.
__device__ __forceinline__ void gload_lds16(const u16* g, u16* lds) {
    __builtin_amdgcn_global_load_lds((__attribute__((address_space(1))) void*)g,
                                     (__attribute__((address_space(3))) void*)lds,
                                     16, 0, 0);
}

// ---------------- fp32 -> bf16 converts ----------------
__global__ __launch_bounds__(256) void cvt_kernel(const float* __restrict__ in,
                                                  u16* __restrict__ out, int n4) {
    int i = blockIdx.x * blockDim.x + threadIdx.x;
    int stride = gridDim.x * blockDim.x;
    for (; i < n4; i += stride) {
        float4 v = ((const float4*)in)[i];
        ushort4 o;
        o.x = f2bf(v.x); o.y = f2bf(v.y); o.z = f2bf(v.z); o.w = f2bf(v.w);
        ((ushort4*)out)[i] = o;
    }
}

// fused Wq|Wk|Wv -> contiguous bf16 [6144][4096]
__global__ __launch_bounds__(256) void cvt_qkv(const float* __restrict__ Wq,
                                               const float* __restrict__ Wk,
                                               const float* __restrict__ Wv,
                                               u16* __restrict__ out) {
    const int n4 = 6144 * 4096 / 4;
    int i = blockIdx.x * blockDim.x + threadIdx.x;
    int stride = gridDim.x * blockDim.x;
    for (; i < n4; i += stride) {
        float4 v;
        if (i < 4194304)       v = ((const float4*)Wq)[i];
        else if (i < 5242880)  v = ((const float4*)Wk)[i - 4194304];
        else                   v = ((const float4*)Wv)[i - 5242880];
        ushort4 o;
        o.x = f2bf(v.x); o.y = f2bf(v.y); o.z = f2bf(v.z); o.w = f2bf(v.w);
        ((ushort4*)out)[i] = o;
    }
}

// ---------------- RoPE cos/sin table ----------------
__global__ __launch_bounds__(256) void rope_table_kernel(float2* __restrict__ tbl) {
    int i = blockIdx.x * blockDim.x + threadIdx.x;
    if (i >= S * 64) return;
    int p = i >> 6, j = i & 63;
    float inv = powf(10000.0f, -(float)j / 64.0f);
    float a = (float)p * inv;
    tbl[i] = make_float2(cosf(a), sinf(a));
}

// ---------------- RoPE in-place on bf16, row stride ld, pair (d, d+64) ----------------
__global__ __launch_bounds__(256) void rope_kernel(u16* __restrict__ X,
                                                   const float2* __restrict__ tbl,
                                                   int nh, int ld, float scale) {
    int i = blockIdx.x * blockDim.x + threadIdx.x;
    int total = S * nh * 64;
    if (i >= total) return;
    int dd = i & 63;
    int t2 = i >> 6;
    int hh = t2 % nh;
    int s  = t2 / nh;
    size_t base = (size_t)s * ld + (size_t)hh * HD + dd;
    float x1 = bf2f(X[base]);
    float x2 = bf2f(X[base + 64]);
    float2 cs = tbl[(s << 6) + dd];
    X[base]      = f2bf((x1 * cs.x - x2 * cs.y) * scale);
    X[base + 64] = f2bf((x2 * cs.x + x1 * cs.y) * scale);
}

// ============== m97-structure 128x128 GEMM (4 waves, BK=64, 2-barrier) ==============
// C = A(MxK) * Bt(NxK)^T, f32 row-major out. LDS T2-swizzled both sides
// (byte ^= (row&7)<<4 on reads; inverse-permuted global source on stage).
__global__ __launch_bounds__(256)
void gemm_bt(const u16* __restrict__ A, const u16* __restrict__ Bt,
             float* __restrict__ C, int M, int N, int K, int lda, int ldb, int ldc) {
    __shared__ u16 Al[128 * 64];
    __shared__ u16 Bl[128 * 64];
    const int t = threadIdx.x;
    const int w = t >> 6, l = t & 63;
    const int r16 = l & 15, g4 = l >> 4;
    const int m0 = blockIdx.y * 128, n0 = blockIdx.x * 128;
    const int wr = (w >> 1) * 64, wc = (w & 1) * 64;

    f32x4 acc[4][4];
#pragma unroll
    for (int i = 0; i < 4; ++i)
#pragma unroll
        for (int j = 0; j < 4; ++j) acc[i][j] = f32x4{0.f, 0.f, 0.f, 0.f};

    for (int kt = 0; kt < K; kt += 64) {
#pragma unroll
        for (int i = 0; i < 4; ++i) {
            int c = i * 256 + t;
            int r = c >> 3, s = (c & 7) ^ (r & 7);
            gload_lds16(A + (size_t)(m0 + r) * lda + kt + (s << 3),
                        Al + ((i * 256 + w * 64) << 3));
        }
#pragma unroll
        for (int i = 0; i < 4; ++i) {
            int c = i * 256 + t;
            int r = c >> 3, s = (c & 7) ^ (r & 7);
            gload_lds16(Bt + (size_t)(n0 + r) * ldb + kt + (s << 3),
                        Bl + ((i * 256 + w * 64) << 3));
        }
        asm volatile("s_waitcnt vmcnt(0)" ::: "memory");
        __syncthreads();

#pragma unroll
        for (int kk = 0; kk < 2; ++kk) {
            bf16x8 af[4], bfr[4];
#pragma unroll
            for (int mi = 0; mi < 4; ++mi) {
                int r = wr + mi * 16 + r16;
                af[mi] = *(const bf16x8*)((const char*)Al +
                          ((r * 128 + kk * 64 + g4 * 16) ^ ((r & 7) << 4)));
            }
#pragma unroll
            for (int ni = 0; ni < 4; ++ni) {
                int r = wc + ni * 16 + r16;
                bfr[ni] = *(const bf16x8*)((const char*)Bl +
                           ((r * 128 + kk * 64 + g4 * 16) ^ ((r & 7) << 4)));
            }
#pragma unroll
            for (int mi = 0; mi < 4; ++mi)
#pragma unroll
                for (int ni = 0; ni < 4; ++ni)
                    mfma16(acc[mi][ni], af[mi], bfr[ni]);
        }
        __syncthreads();
    }

    const int rb = g4 * 4;
#pragma unroll
    for (int mi = 0; mi < 4; ++mi)
#pragma unroll
        for (int ni = 0; ni < 4; ++ni) {
            const int n = n0 + wc + ni * 16 + r16;
            const int mbase = m0 + wr + mi * 16 + rb;
#pragma unroll
            for (int j = 0; j < 4; ++j)
                C[(size_t)(mbase + j) * ldc + n] = acc[mi][ni][j];
        }
}

// ---------------- fused QKV GEMM: X[2048][4096] * Wqkv[6144][4096]^T ----------------
// n < 5120 -> Cqk[m][n] bf16 (stride LDQ).  n >= 5120 -> Vt[n-5120][m] bf16 (stride S).
__global__ __launch_bounds__(256)
void gemm_qkv(const u16* __restrict__ A, const u16* __restrict__ Bt,
              u16* __restrict__ Cqk, u16* __restrict__ Vt) {
    __shared__ u16 Al[128 * 64];
    __shared__ u16 Bl[128 * 64];
    const int t = threadIdx.x;
    const int w = t >> 6, l = t & 63;
    const int r16 = l & 15, g4 = l >> 4;
    const int m0 = blockIdx.y * 128, n0 = blockIdx.x * 128;
    const int wr = (w >> 1) * 64, wc = (w & 1) * 64;

    f32x4 acc[4][4];
#pragma unroll
    for (int i = 0; i < 4; ++i)
#pragma unroll
        for (int j = 0; j < 4; ++j) acc[i][j] = f32x4{0.f, 0.f, 0.f, 0.f};

    for (int kt = 0; kt < DM; kt += 64) {
#pragma unroll
        for (int i = 0; i < 4; ++i) {
            int c = i * 256 + t;
            int r = c >> 3, s = (c & 7) ^ (r & 7);
            gload_lds16(A + (size_t)(m0 + r) * DM + kt + (s << 3),
                        Al + ((i * 256 + w * 64) << 3));
        }
#pragma unroll
        for (int i = 0; i < 4; ++i) {
            int c = i * 256 + t;
            int r = c >> 3, s = (c & 7) ^ (r & 7);
            gload_lds16(Bt + (size_t)(n0 + r) * DM + kt + (s << 3),
                        Bl + ((i * 256 + w * 64) << 3));
        }
        asm volatile("s_waitcnt vmcnt(0)" ::: "memory");
        __syncthreads();

#pragma unroll
        for (int kk = 0; kk < 2; ++kk) {
            bf16x8 af[4], bfr[4];
#pragma unroll
            for (int mi = 0; mi < 4; ++mi) {
                int r = wr + mi * 16 + r16;
                af[mi] = *(const bf16x8*)((const char*)Al +
                          ((r * 128 + kk * 64 + g4 * 16) ^ ((r & 7) << 4)));
            }
#pragma unroll
            for (int ni = 0; ni < 4; ++ni) {
                int r = wc + ni * 16 + r16;
                bfr[ni] = *(const bf16x8*)((const char*)Bl +
                           ((r * 128 + kk * 64 + g4 * 16) ^ ((r & 7) << 4)));
            }
#pragma unroll
            for (int mi = 0; mi < 4; ++mi)
#pragma unroll
                for (int ni = 0; ni < 4; ++ni)
                    mfma16(acc[mi][ni], af[mi], bfr[ni]);
        }
        __syncthreads();
    }

    const int rb = g4 * 4;
    if (n0 < 5120) {  // Q|K region, row-major
#pragma unroll
        for (int mi = 0; mi < 4; ++mi)
#pragma unroll
            for (int ni = 0; ni < 4; ++ni) {
                const int n = n0 + wc + ni * 16 + r16;
                const int mbase = m0 + wr + mi * 16 + rb;
#pragma unroll
                for (int j = 0; j < 4; ++j)
                    Cqk[(size_t)(mbase + j) * LDQ + n] = f2bf(acc[mi][ni][j]);
            }
    } else {          // V region, transposed into Vt[1024][2048]
#pragma unroll
        for (int mi = 0; mi < 4; ++mi)
#pragma unroll
            for (int ni = 0; ni < 4; ++ni) {
                const int n = n0 + wc + ni * 16 + r16 - 5120;
                const int mbase = m0 + wr + mi * 16 + rb;
                ushort4 v4;
                v4.x = f2bf(acc[mi][ni][0]); v4.y = f2bf(acc[mi][ni][1]);
                v4.z = f2bf(acc[mi][ni][2]); v4.w = f2bf(acc[mi][ni][3]);
                *(ushort4*)&Vt[(size_t)n * S + mbase] = v4;
            }
    }
}

// ---------------- causal GQA flash attention (8 waves, 128-row supertiles) ----------------
// grid (8, 32): block p handles q-supertiles p and 15-p (128 rows each); work is
// exactly 34 kv-tile computes per block. One KV stage serves BOTH supertiles and
// all 8 waves (2x the MFMA density per staged byte of the 4-wave version).
// Q pre-scaled by log2(e)/sqrt(128) (exp2-domain softmax). Vt bf16 [NKV*128][S].
// All LDS XOR-swizzled (byte ^= (row&7)<<4), inverse-permuted global source.
__global__ __launch_bounds__(512, 2)
void attn_fwd(const u16* __restrict__ QK, const u16* __restrict__ Vt,
              u16* __restrict__ O) {
    __shared__ u16 Kl[2][64 * 128];   // 2 x 16KB
    __shared__ u16 Vl[2][128 * 64];   // 2 x 16KB
    __shared__ u16 Pl[8 * 16 * 64];   // 16KB, per-wave 2KB

    const int t = threadIdx.x;
    const int w = t >> 6, l = t & 63;
    const int r16 = l & 15, g4 = l >> 4;
    const int h = blockIdx.y;
    const int kvh = h >> 2;
    const int p = blockIdx.x;                 // 0..7
    const int q0A = p * 128, q0B = (15 - p) * 128;
    const int ntA = 2 * p + 2, ntB = 32 - 2 * p;   // ntA <= ntB

    const u16* Kg = QK + 4096 + kvh * HD;
    const u16* Vg = Vt + (size_t)(kvh * HD) * S;
    u16* Pb = &Pl[w * 1024];

    bf16x8 qfA[4], qfB[4];
    {
        const u16* Qg = QK + h * HD;
        const size_t qrA = (size_t)(q0A + w * 16 + r16) * LDQ;
        const size_t qrB = (size_t)(q0B + w * 16 + r16) * LDQ;
#pragma unroll
        for (int kg = 0; kg < 4; ++kg) {
            qfA[kg] = *(const bf16x8*)&Qg[qrA + kg * 32 + g4 * 8];
            qfB[kg] = *(const bf16x8*)&Qg[qrB + kg * 32 + g4 * 8];
        }
    }

    f32x4 accA[8], accB[8];
    float mA[4], lA[4], mB[4], lB[4];
#pragma unroll
    for (int i = 0; i < 8; ++i) { accA[i] = f32x4{0,0,0,0}; accB[i] = f32x4{0,0,0,0}; }
#pragma unroll
    for (int j = 0; j < 4; ++j) { mA[j] = -3.0e38f; lA[j] = 0.f; mB[j] = -3.0e38f; lB[j] = 0.f; }

    // stage KV tile tk into buffer b; 512 threads -> 2 gloads per array
    auto stage = [&](int tk, int b) {
        const int kv0 = tk * 64;
#pragma unroll
        for (int i = 0; i < 2; ++i) {   // K: 64 rows x 256B (16 slots/row)
            int c = i * 512 + t;
            int r = c >> 4, s = (c & 15) ^ (r & 7);
            gload_lds16(Kg + (size_t)(kv0 + r) * LDQ + (s << 3),
                        &Kl[b][0] + ((i * 512 + w * 64) << 3));
        }
#pragma unroll
        for (int i = 0; i < 2; ++i) {   // Vt: 128 rows x 128B (8 slots/row)
            int c = i * 512 + t;
            int r = c >> 3, s = (c & 7) ^ (r & 7);
            gload_lds16(Vg + (size_t)r * S + kv0 + (s << 3),
                        &Vl[b][0] + ((i * 512 + w * 64) << 3));
        }
    };

    auto compute = [&](f32x4 (&acco)[8], float (&mrun)[4], float (&lrun)[4],
                       const bf16x8 (&qf)[4], int q0, int tk, int b) {
        const int kv0 = tk * 64;
        const bool maskit = (kv0 + 63 > q0 + (w << 4));   // wave-uniform
        const u16* Kb = &Kl[b][0];
        const u16* Vb = &Vl[b][0];

        f32x4 sc[4];
#pragma unroll
        for (int ni = 0; ni < 4; ++ni) sc[ni] = f32x4{0,0,0,0};
        __builtin_amdgcn_s_setprio(1);
#pragma unroll
        for (int kg = 0; kg < 4; ++kg) {
#pragma unroll
            for (int ni = 0; ni < 4; ++ni) {
                int row = ni * 16 + r16;
                int bb = (row * 256 + kg * 64 + g4 * 16) ^ ((row & 7) << 4);
                bf16x8 kf = *(const bf16x8*)((const char*)Kb + bb);
                mfma16(sc[ni], qf[kg], kf);
            }
        }
        __builtin_amdgcn_s_setprio(0);

        float vmax[4];
        bool grow = false;
#pragma unroll
        for (int j = 0; j < 4; ++j) {
            if (maskit) {
                const int qg = q0 + w * 16 + g4 * 4 + j;
#pragma unroll
                for (int ni = 0; ni < 4; ++ni)
                    if (kv0 + ni * 16 + r16 > qg) sc[ni][j] = -3.0e38f;
            }
            float v = fmaxf(fmaxf(sc[0][j], sc[1][j]), fmaxf(sc[2][j], sc[3][j]));
            v = fmaxf(v, __shfl_xor(v, 1, 16));
            v = fmaxf(v, __shfl_xor(v, 2, 16));
            v = fmaxf(v, __shfl_xor(v, 4, 16));
            v = fmaxf(v, __shfl_xor(v, 8, 16));
            vmax[j] = v;
            grow = grow || (v > mrun[j] + 11.5f);   // defer-max (T13)
        }
        float fac[4] = {1.f, 1.f, 1.f, 1.f};
        if (__any(grow)) {
#pragma unroll
            for (int j = 0; j < 4; ++j) {
                float nm = fmaxf(mrun[j], vmax[j]);
                fac[j] = exp2f(mrun[j] - nm);
                mrun[j] = nm;
            }
#pragma unroll
            for (int i = 0; i < 8; ++i)
#pragma unroll
                for (int j = 0; j < 4; ++j) acco[i][j] *= fac[j];
        }
#pragma unroll
        for (int j = 0; j < 4; ++j) {
            float p0 = exp2f(sc[0][j] - mrun[j]);
            float p1 = exp2f(sc[1][j] - mrun[j]);
            float p2 = exp2f(sc[2][j] - mrun[j]);
            float p3 = exp2f(sc[3][j] - mrun[j]);
            sc[0][j] = p0; sc[1][j] = p1; sc[2][j] = p2; sc[3][j] = p3;
            float s2 = (p0 + p1) + (p2 + p3);
            s2 += __shfl_xor(s2, 1, 16);
            s2 += __shfl_xor(s2, 2, 16);
            s2 += __shfl_xor(s2, 4, 16);
            s2 += __shfl_xor(s2, 8, 16);
            lrun[j] = lrun[j] * fac[j] + s2;
        }

        // P (D-layout) -> swizzled per-wave LDS -> A-operand layout
#pragma unroll
        for (int ni = 0; ni < 4; ++ni)
#pragma unroll
            for (int j = 0; j < 4; ++j) {
                int row = g4 * 4 + j;
                int bb = (row * 128 + ((ni * 16 + r16) << 1)) ^ ((row & 7) << 4);
                *(u16*)((char*)Pb + bb) = f2bf(sc[ni][j]);
            }
        asm volatile("s_waitcnt lgkmcnt(0)" ::: "memory");
        __builtin_amdgcn_sched_barrier(0);

        int pb0 = (r16 * 128 + g4 * 16) ^ ((r16 & 7) << 4);
        bf16x8 pf0 = *(const bf16x8*)((const char*)Pb + pb0);
        bf16x8 pf1 = *(const bf16x8*)((const char*)Pb + (pb0 ^ 64));
        __builtin_amdgcn_s_setprio(1);
#pragma unroll
        for (int ni = 0; ni < 8; ++ni) {
            int row = ni * 16 + r16;
            int bb = (row * 128 + g4 * 16) ^ ((row & 7) << 4);
            bf16x8 v0 = *(const bf16x8*)((const char*)Vb + bb);
            mfma16(acco[ni], pf0, v0);
            bf16x8 v1 = *(const bf16x8*)((const char*)Vb + (bb ^ 64));
            mfma16(acco[ni], pf1, v1);
        }
        __builtin_amdgcn_s_setprio(0);
    };

    auto epilogue = [&](f32x4 (&acco)[8], float (&lrun)[4], int q0) {
        float rl[4];
#pragma unroll
        for (int j = 0; j < 4; ++j) rl[j] = 1.0f / lrun[j];
#pragma unroll
        for (int ni = 0; ni < 8; ++ni)
#pragma unroll
            for (int j = 0; j < 4; ++j) {
                const int qg = q0 + w * 16 + g4 * 4 + j;
                O[(size_t)qg * DM + h * HD + ni * 16 + r16] = f2bf(acco[ni][j] * rl[j]);
            }
    };

    stage(0, 0);
    asm volatile("s_waitcnt vmcnt(0)" ::: "memory");
    __syncthreads();
    int buf = 0;

    for (int tk = 0; tk < ntB; ++tk) {
        if (tk + 1 < ntB) stage(tk + 1, buf ^ 1);
        compute(accB, mB, lB, qfB, q0B, tk, buf);
        if (tk < ntA) compute(accA, mA, lA, qfA, q0A, tk, buf);
        asm volatile("s_waitcnt vmcnt(0)" ::: "memory");
        __syncthreads();
        buf ^= 1;
    }
    epilogue(accA, lA, q0A);
    epilogue(accB, lB, q0B);
}

// ---------------- launch ----------------
extern "C" void kernel_launch(void* const* d_in, const int* in_sizes, int n_in,
                              void* d_out, int out_size, void* d_ws, size_t ws_size,
                              hipStream_t stream) {
    const float* X  = (const float*)d_in[0];
    // d_in[1] = position_ids (arange(S) by construction)
    const float* Wq = (const float*)d_in[2];
    const float* Wk = (const float*)d_in[3];
    const float* Wv = (const float*)d_in[4];
    const float* Wo = (const float*)d_in[5];

    char* ws = (char*)d_ws;
    u16*    Xbf  = (u16*)(ws + 0);            // 2048x4096 bf16 = 16,777,216
    u16*    Wqkv = (u16*)(ws + 16777216);     // 6144x4096 bf16 = 50,331,648
    u16*    Wobf = (u16*)(ws + 67108864);     // 4096x4096 bf16 = 33,554,432
    u16*    QKb  = (u16*)(ws + 100663296);    // 2048x5120 bf16 = 20,971,520
    u16*    Vtbf = (u16*)(ws + 121634816);    // 1024x2048 bf16 =  4,194,304 (V^T)
    u16*    Obf  = (u16*)(ws + 125829120);    // 2048x4096 bf16 = 16,777,216
    float2* tbl  = (float2*)(ws + 142606336); // 2048x64 float2 =  1,048,576
    if (ws_size < 143654912ull) return;

    dim3 blk(256);

    cvt_kernel<<<2048, blk, 0, stream>>>(X,  Xbf,  S * DM / 4);
    cvt_qkv<<<2048, blk, 0, stream>>>(Wq, Wk, Wv, Wqkv);
    cvt_kernel<<<2048, blk, 0, stream>>>(Wo, Wobf, DM * DM / 4);
    rope_table_kernel<<<(S * 64 + 255) / 256, blk, 0, stream>>>(tbl);

    // fused QKV projection: m97 128^2, grid 48x16 = 768 blocks (3/CU)
    gemm_qkv<<<dim3(48, 16), blk, 0, stream>>>(Xbf, Wqkv, QKb, Vtbf);

    // RoPE; Q folds in log2(e)*HD^-0.5 so softmax runs in exp2 domain
    rope_kernel<<<(S * NH * 64 + 255) / 256, blk, 0, stream>>>(
        QKb, tbl, NH, LDQ, 0.08838834764831845f * 1.4426950408889634f);
    rope_kernel<<<(S * NKV * 64 + 255) / 256, blk, 0, stream>>>(
        QKb + 4096, tbl, NKV, LDQ, 1.0f);

    // attention: 8 waves, 128-row supertile pairs, grid (8,32) = 256 blocks
    attn_fwd<<<dim3(8, NH), dim3(512), 0, stream>>>(QKb, Vtbf, Obf);

    // output projection -> fp32: m97 128^2, grid 32x16 = 512 blocks (2/CU)
    gemm_bt<<<dim3(DM / 128, S / 128), blk, 0, stream>>>(
        Obf, Wobf, (float*)d_out, S, DM, DM, DM, DM, DM);
}